// Round 9
// baseline (96.792 us; speedup 1.0000x reference)
//
#include <hip/hip_runtime.h>
#include <hip/hip_cooperative_groups.h>

namespace cg = cooperative_groups;

typedef float f32x4 __attribute__((ext_vector_type(4)));

constexpr int IN_F  = 8192;
constexpr int OUT_F = 8192;
constexpr int BATCH = 4096;
constexpr int TPB   = 256;
constexpr int S4    = IN_F / 4;          // f32x4 per row

// ---- fused coop config: 1024 blocks = 4/CU (16 waves/CU) ----
constexpr int NBLK    = 1024;
constexpr int CHUNKS  = NBLK / 8;        // 128 row-chunks (8 col-groups)
constexpr int RPC     = OUT_F / CHUNKS;  // 64 rows per chunk
constexpr int ROWS    = BATCH / NBLK;    // 4 batch rows per block in phase 3

__global__ __launch_bounds__(TPB, 4) void fused2_kernel(
    const float* __restrict__ x, const float* __restrict__ W,
    const float* __restrict__ bias, float* __restrict__ out,
    float* __restrict__ part, float* __restrict__ wsum,
    float* __restrict__ bsum) {

    __shared__ float lds[TPB];
    __shared__ float red[16];
    const int tid = threadIdx.x, blk = blockIdx.x;

    const long rowbase = (long)blk * ROWS;
    const f32x4* __restrict__ x4 =
        reinterpret_cast<const f32x4*>(x) + rowbase * S4;

    // ---- Phase 1: strided colsum (proven rate), partials = 4 MB ----
    {
        const int g = blk & 7, c = blk >> 3;
        const f32x4* __restrict__ p = reinterpret_cast<const f32x4*>(W)
            + (long)c * RPC * S4 + g * TPB + tid;
        f32x4 a0 = {0.f,0.f,0.f,0.f}, a1 = {0.f,0.f,0.f,0.f};
        #pragma unroll 8
        for (int r = 0; r < RPC; r += 2) {
            a0 += p[(long)r * S4];
            a1 += p[(long)(r + 1) * S4];
        }
        reinterpret_cast<f32x4*>(part)[(long)c * S4 + g * TPB + tid] = a0 + a1;
    }

    // ---- x register-prefetch (rows 0,1) issued BEFORE the grid sync:
    //      these 16 loads/thread stream from HBM concurrently with other
    //      blocks' phase-1 tails and the combine phase (T14-style split).
    f32x4 pf0[8], pf1[8];
    #pragma unroll
    for (int j = 0; j < 8; ++j) pf0[j] = x4[j * TPB + tid];
    #pragma unroll
    for (int j = 0; j < 8; ++j) pf1[j] = x4[S4 + j * TPB + tid];

    cg::this_grid().sync();

    // ---- Phase 2: parallel combine (blocks 0..255) + bias (block 256) ----
    if (blk < 256) {
        const int col = blk * 32 + (tid & 31);
        const int sl  = tid >> 5;                 // 8 slices x 16 chunks
        float s = 0.f;
        #pragma unroll
        for (int k = 0; k < CHUNKS / 8; ++k)
            s += part[(long)(sl * (CHUNKS / 8) + k) * IN_F + col];
        lds[tid] = s;
        __syncthreads();
        if (tid < 32) {
            float t = 0.f;
            #pragma unroll
            for (int q = 0; q < 8; ++q) t += lds[q * 32 + tid];
            wsum[blk * 32 + tid] = t;
        }
    } else if (blk == 256) {
        float bs = 0.f;
        for (int k = tid; k < OUT_F; k += TPB) bs += bias[k];
        #pragma unroll
        for (int o = 32; o; o >>= 1) bs += __shfl_down(bs, o);
        if ((tid & 63) == 0) red[tid >> 6] = bs;
        __syncthreads();
        if (tid == 0) *bsum = red[0] + red[1] + red[2] + red[3];
    }

    cg::this_grid().sync();

    // ---- Phase 3: 4 rows per block (rows 0,1 from prefetch regs) ----
    {
        const f32x4* __restrict__ w4 = reinterpret_cast<const f32x4*>(wsum);
        float s0 = 0.f, s1 = 0.f, s2 = 0.f, s3 = 0.f;
        #pragma unroll
        for (int j = 0; j < 8; ++j) {
            const int k = j * TPB + tid;
            f32x4 wv = w4[k];
            f32x4 a  = pf0[j];
            f32x4 b  = pf1[j];
            f32x4 c2 = x4[2 * S4 + k];
            f32x4 d  = x4[3 * S4 + k];
            s0 += a.x*wv.x + a.y*wv.y + a.z*wv.z + a.w*wv.w;
            s1 += b.x*wv.x + b.y*wv.y + b.z*wv.z + b.w*wv.w;
            s2 += c2.x*wv.x + c2.y*wv.y + c2.z*wv.z + c2.w*wv.w;
            s3 += d.x*wv.x + d.y*wv.y + d.z*wv.z + d.w*wv.w;
        }
        #pragma unroll
        for (int o = 32; o; o >>= 1) {
            s0 += __shfl_down(s0, o);
            s1 += __shfl_down(s1, o);
            s2 += __shfl_down(s2, o);
            s3 += __shfl_down(s3, o);
        }
        const int wid = tid >> 6;
        if ((tid & 63) == 0) {
            red[wid] = s0; red[4 + wid] = s1; red[8 + wid] = s2; red[12 + wid] = s3;
        }
        __syncthreads();
        if (tid == 0) {
            const float bsv = *bsum;
            out[rowbase + 0] = (red[0] +red[1] +red[2] +red[3]  + bsv) * (1.0f/OUT_F);
            out[rowbase + 1] = (red[4] +red[5] +red[6] +red[7]  + bsv) * (1.0f/OUT_F);
            out[rowbase + 2] = (red[8] +red[9] +red[10]+red[11] + bsv) * (1.0f/OUT_F);
            out[rowbase + 3] = (red[12]+red[13]+red[14]+red[15] + bsv) * (1.0f/OUT_F);
        }
    }
}

// ---------------- fallback: proven R8 3-kernel path (95.8 us) ---------------
constexpr int CH_FB = 256;
constexpr int COLG  = IN_F / (TPB * 4);   // 8

__global__ __launch_bounds__(TPB) void colsum_fb_kernel(
    const float* __restrict__ W, float* __restrict__ part, int rpc) {
    const int col4 = blockIdx.x * TPB + threadIdx.x;
    const f32x4* __restrict__ p = reinterpret_cast<const f32x4*>(W)
        + (long)blockIdx.y * rpc * S4 + col4;
    f32x4 a0 = {0.f,0.f,0.f,0.f}, a1 = {0.f,0.f,0.f,0.f};
    #pragma unroll 8
    for (int r = 0; r < rpc; r += 2) {
        a0 += p[(long)r * S4];
        a1 += p[(long)(r + 1) * S4];
    }
    reinterpret_cast<f32x4*>(part)[(long)blockIdx.y * S4 + col4] = a0 + a1;
}

__global__ __launch_bounds__(TPB) void combine_fb_kernel(
    const float* __restrict__ part, const float* __restrict__ bias,
    float* __restrict__ wsum, float* __restrict__ bsum, int chunks) {
    const int blk = blockIdx.x, tid = threadIdx.x;
    if (blk < 256) {
        __shared__ float lds[TPB];
        const int col = blk * 32 + (tid & 31);
        const int sl  = tid >> 5;
        float s = 0.f;
        for (int k = 0; k < chunks / 8; ++k)
            s += part[(long)(sl * (chunks / 8) + k) * IN_F + col];
        lds[tid] = s;
        __syncthreads();
        if (tid < 32) {
            float t = 0.f;
            #pragma unroll
            for (int q = 0; q < 8; ++q) t += lds[q * 32 + tid];
            wsum[blk * 32 + tid] = t;
        }
    } else {
        __shared__ float red[4];
        float bs = 0.f;
        for (int k = tid; k < OUT_F; k += TPB) bs += bias[k];
        #pragma unroll
        for (int o = 32; o; o >>= 1) bs += __shfl_down(bs, o);
        if ((tid & 63) == 0) red[tid >> 6] = bs;
        __syncthreads();
        if (tid == 0) *bsum = red[0] + red[1] + red[2] + red[3];
    }
}

__global__ __launch_bounds__(TPB) void rowdot_fb_kernel(
    const float* __restrict__ x, const float* __restrict__ wsum,
    const float* __restrict__ bsum, float* __restrict__ out) {
    __shared__ float red[4];
    const int tid = threadIdx.x;
    const long b  = blockIdx.x;
    const f32x4* __restrict__ x4 = reinterpret_cast<const f32x4*>(x) + b * S4;
    const f32x4* __restrict__ w4 = reinterpret_cast<const f32x4*>(wsum);
    float s = 0.f;
    #pragma unroll
    for (int j = 0; j < 8; ++j) {
        f32x4 a = x4[j * TPB + tid];
        f32x4 w = w4[j * TPB + tid];
        s += a.x*w.x + a.y*w.y + a.z*w.z + a.w*w.w;
    }
    #pragma unroll
    for (int o = 32; o; o >>= 1) s += __shfl_down(s, o);
    if ((tid & 63) == 0) red[tid >> 6] = s;
    __syncthreads();
    if (tid == 0)
        out[b] = (red[0] + red[1] + red[2] + red[3] + *bsum) * (1.0f / OUT_F);
}

extern "C" void kernel_launch(void* const* d_in, const int* in_sizes, int n_in,
                              void* d_out, int out_size, void* d_ws, size_t ws_size,
                              hipStream_t stream) {
    const float* x    = (const float*)d_in[0];  // [BATCH, IN_F]
    const float* W    = (const float*)d_in[1];  // [OUT_F, IN_F]
    const float* bias = (const float*)d_in[2];  // [OUT_F]
    float*       out  = (float*)d_out;          // [BATCH]

    // Capture-safe host queries -> deterministic path choice.
    int dev = 0;    (void)hipGetDevice(&dev);
    int coop = 0;   (void)hipDeviceGetAttribute(&coop, hipDeviceAttributeCooperativeLaunch, dev);
    int ncu = 0;    (void)hipDeviceGetAttribute(&ncu, hipDeviceAttributeMultiprocessorCount, dev);
    int maxblk = 0;
    (void)hipOccupancyMaxActiveBlocksPerMultiprocessor(&maxblk, fused2_kernel, TPB, 0);

    const size_t need_c = ((size_t)CHUNKS * IN_F + IN_F + 16) * sizeof(float);
    if (coop && (long)maxblk * ncu >= NBLK && need_c <= ws_size) {
        float* part = (float*)d_ws;
        float* wsum = part + (size_t)CHUNKS * IN_F;
        float* bsum = wsum + IN_F;
        void* args[] = {(void*)&x, (void*)&W, (void*)&bias, (void*)&out,
                        (void*)&part, (void*)&wsum, (void*)&bsum};
        hipError_t err = hipLaunchCooperativeKernel(
            (const void*)fused2_kernel, dim3(NBLK), dim3(TPB), args, 0, stream);
        if (err == hipSuccess) return;
    }

    // fallback: proven 3-kernel path
    int chunks = CH_FB;
    while (chunks > 8 &&
           ((size_t)chunks * IN_F + IN_F + 16) * sizeof(float) > ws_size)
        chunks >>= 1;
    float* part = (float*)d_ws;
    float* wsum = part + (size_t)chunks * IN_F;
    float* bsum = wsum + IN_F;
    colsum_fb_kernel<<<dim3(COLG, chunks), TPB, 0, stream>>>(W, part, OUT_F / chunks);
    combine_fb_kernel<<<257, TPB, 0, stream>>>(part, bias, wsum, bsum, chunks);
    rowdot_fb_kernel<<<BATCH, TPB, 0, stream>>>(x, wsum, bsum, out);
}

// Round 10
// 95.820 us; speedup vs baseline: 1.0101x; 1.0101x over previous
//
#include <hip/hip_runtime.h>

typedef float f32x4 __attribute__((ext_vector_type(4)));

constexpr int IN_F  = 8192;
constexpr int OUT_F = 8192;
constexpr int BATCH = 4096;
constexpr int TPB   = 256;
constexpr int S4    = IN_F / 4;            // f32x4 per row

// ---- main (contiguous) path ----
constexpr int CHUNKS = 1024;               // 8 rows per chunk
constexpr int RPCH   = OUT_F / CHUNKS;     // 8
// ---- fallback (strided, small ws) path ----
constexpr int CHUNKS_FB = 256;
constexpr int COLG      = IN_F / (TPB * 4);   // 8

// ---------------------------------------------------------------------------
// Kernel A: column sums of W, CONTIGUOUS streaming (best measured: R8).
//   Block c owns rows [8c, 8c+8) = 256 KB of W, read fully sequentially.
//   Each thread accumulates 8 f32x4 column-slots (static indices -> VGPRs).
//   grid = 1024 (4/CU), block = 256.
// ---------------------------------------------------------------------------
__global__ __launch_bounds__(TPB, 4) void colsum_contig_kernel(
    const float* __restrict__ W, float* __restrict__ part) {
    const int tid = threadIdx.x, c = blockIdx.x;
    const f32x4* __restrict__ p =
        reinterpret_cast<const f32x4*>(W) + (long)c * RPCH * S4;
    f32x4 acc[8] = {};
    #pragma unroll
    for (int r = 0; r < RPCH; ++r) {
        #pragma unroll
        for (int j = 0; j < 8; ++j)
            acc[j] += p[(long)r * S4 + j * TPB + tid];
    }
    f32x4* o = reinterpret_cast<f32x4*>(part) + (long)c * S4;
    #pragma unroll
    for (int j = 0; j < 8; ++j) o[j * TPB + tid] = acc[j];
}

// ---------------------------------------------------------------------------
// Kernel B: combine 1024 partials -> wsum. 128 blocks x 64 columns,
//   4 slices of 256 chunks each (fixed order, deterministic). blk 128 = bias.
//   grid = 129, block = 256.
// ---------------------------------------------------------------------------
__global__ __launch_bounds__(TPB) void combine_c_kernel(
    const float* __restrict__ part, const float* __restrict__ bias,
    float* __restrict__ wsum, float* __restrict__ bsum) {
    const int blk = blockIdx.x, tid = threadIdx.x;
    if (blk < IN_F / 64) {
        __shared__ float lds[TPB];
        const int col = blk * 64 + (tid & 63);
        const int sl  = tid >> 6;              // 4 slices x 256 chunks
        float s = 0.f;
        #pragma unroll 8
        for (int k = 0; k < CHUNKS / 4; ++k)
            s += part[(long)(sl * (CHUNKS / 4) + k) * IN_F + col];
        lds[tid] = s;
        __syncthreads();
        if (tid < 64)
            wsum[blk * 64 + tid] =
                lds[tid] + lds[64 + tid] + lds[128 + tid] + lds[192 + tid];
    } else {
        __shared__ float red[4];
        float bs = 0.f;
        for (int k = tid; k < OUT_F; k += TPB) bs += bias[k];
        #pragma unroll
        for (int o = 32; o; o >>= 1) bs += __shfl_down(bs, o);
        if ((tid & 63) == 0) red[tid >> 6] = bs;
        __syncthreads();
        if (tid == 0) *bsum = red[0] + red[1] + red[2] + red[3];
    }
}

// ---------------------------------------------------------------------------
// Kernel C: out[b] = (dot(x[b,:], wsum) + bsum) / OUT_F
//   1 row per block, 4096 blocks (16/CU): max TLP, short chains, small tail.
//   wsum (32 KB) is L2-resident — no LDS staging.
// ---------------------------------------------------------------------------
__global__ __launch_bounds__(TPB) void rowdot1_kernel(
    const float* __restrict__ x, const float* __restrict__ wsum,
    const float* __restrict__ bsum, float* __restrict__ out) {
    __shared__ float red[4];
    const int tid = threadIdx.x;
    const long b  = blockIdx.x;
    const f32x4* __restrict__ x4 = reinterpret_cast<const f32x4*>(x) + b * S4;
    const f32x4* __restrict__ w4 = reinterpret_cast<const f32x4*>(wsum);
    float s = 0.f;
    #pragma unroll
    for (int j = 0; j < 8; ++j) {
        f32x4 a = x4[j * TPB + tid];
        f32x4 w = w4[j * TPB + tid];
        s += a.x * w.x + a.y * w.y + a.z * w.z + a.w * w.w;
    }
    #pragma unroll
    for (int o = 32; o; o >>= 1) s += __shfl_down(s, o);
    if ((tid & 63) == 0) red[tid >> 6] = s;
    __syncthreads();
    if (tid == 0)
        out[b] = (red[0] + red[1] + red[2] + red[3] + *bsum) * (1.0f / OUT_F);
}

// ---------------- fallback kernels (ws too small for 32 MB partials) --------
__global__ __launch_bounds__(TPB) void colsum_strided_kernel(
    const float* __restrict__ W, float* __restrict__ part, int rpc) {
    const int col4 = blockIdx.x * TPB + threadIdx.x;
    const f32x4* __restrict__ p = reinterpret_cast<const f32x4*>(W)
        + (long)blockIdx.y * rpc * S4 + col4;
    f32x4 a0 = {0.f,0.f,0.f,0.f}, a1 = {0.f,0.f,0.f,0.f};
    #pragma unroll 8
    for (int r = 0; r < rpc; r += 2) {
        a0 += p[(long)r * S4];
        a1 += p[(long)(r + 1) * S4];
    }
    reinterpret_cast<f32x4*>(part)[(long)blockIdx.y * S4 + col4] = a0 + a1;
}

__global__ __launch_bounds__(TPB) void combine_fb_kernel(
    const float* __restrict__ part, const float* __restrict__ bias,
    float* __restrict__ wsum, float* __restrict__ bsum, int chunks) {
    const int blk = blockIdx.x, tid = threadIdx.x;
    if (blk < 32) {
        const int col = blk * TPB + tid;
        float s = 0.f;
        #pragma unroll 8
        for (int c = 0; c < chunks; ++c) s += part[(long)c * IN_F + col];
        wsum[col] = s;
    } else {
        __shared__ float red[4];
        float bs = 0.f;
        for (int k = tid; k < OUT_F; k += TPB) bs += bias[k];
        #pragma unroll
        for (int o = 32; o; o >>= 1) bs += __shfl_down(bs, o);
        if ((tid & 63) == 0) red[tid >> 6] = bs;
        __syncthreads();
        if (tid == 0) *bsum = red[0] + red[1] + red[2] + red[3];
    }
}

extern "C" void kernel_launch(void* const* d_in, const int* in_sizes, int n_in,
                              void* d_out, int out_size, void* d_ws, size_t ws_size,
                              hipStream_t stream) {
    const float* x    = (const float*)d_in[0];  // [BATCH, IN_F]
    const float* W    = (const float*)d_in[1];  // [OUT_F, IN_F]
    const float* bias = (const float*)d_in[2];  // [OUT_F]
    float*       out  = (float*)d_out;          // [BATCH]

    if (((size_t)CHUNKS * IN_F + IN_F + 16) * sizeof(float) <= ws_size) {
        // main path (R8 best): contiguous colsum, 32 MB partials
        float* part = (float*)d_ws;
        float* wsum = part + (size_t)CHUNKS * IN_F;
        float* bsum = wsum + IN_F;
        colsum_contig_kernel<<<CHUNKS, TPB, 0, stream>>>(W, part);
        combine_c_kernel<<<IN_F / 64 + 1, TPB, 0, stream>>>(part, bias, wsum, bsum);
        rowdot1_kernel<<<BATCH, TPB, 0, stream>>>(x, wsum, bsum, out);
    } else {
        // fallback: strided colsum, shrink chunks to fit ws
        int chunks = CHUNKS_FB;
        while (chunks > 1 &&
               ((size_t)chunks * IN_F + IN_F + 16) * sizeof(float) > ws_size)
            chunks >>= 1;
        float* part = (float*)d_ws;
        float* wsum = part + (size_t)chunks * IN_F;
        float* bsum = wsum + IN_F;
        colsum_strided_kernel<<<dim3(COLG, chunks), TPB, 0, stream>>>(
            W, part, OUT_F / chunks);
        combine_fb_kernel<<<33, TPB, 0, stream>>>(part, bias, wsum, bsum, chunks);
        rowdot1_kernel<<<BATCH, TPB, 0, stream>>>(x, wsum, bsum, out);
    }
}